// Round 1
// 1104.875 us; speedup vs baseline: 1.3109x; 1.3109x over previous
//
#include <hip/hip_runtime.h>
#include <stdint.h>

// Constrained Viterbi decode, B=64, T=2048, N=32. 64 blocks x 512 threads.
//
// v2 theory: previous version (256 thr, 3 workers, RING=16) compiled to
// VGPR_Count=72 while workers declared buf[4][16]+tp[16]+... (~130 regs of
// intended live state) -> the HBM prefetch buffer spilled to scratch.
// rocprof smoking gun: WRITE_SIZE = 514 MB/dispatch (expected ~0.6 MB)
// ~= 4 KB/block/step of scratch round-trip, exposing ~900cy HBM latency per
// tile inside the producer loop, amplified by a 6-step elasticity window.
//
// Fixes: 7 worker waves (1 tile / 7 steps each, buf[3][16]=48 VGPR - fits),
// RING 16->32 (back[] moved from LDS to d_ws workspace; staged back to LDS
// for the epilogue), publish/poll every 8 steps with packed int4 flag reads,
// self-serving gate loops (deadlock-proof), s_setprio(1) on wave0.
// Arithmetic order of the recurrence is UNCHANGED -> bit-exact outputs.

static constexpr int TT = 2048;
static constexpr int RING = 32;            // eff ring slots (power of 2)
static constexpr int CS = 36;              // col stride (dwords): 144B, 16B-aligned
static constexpr int TILE_DW = 32 * CS;    // 1152 dwords / tile
static constexpr int OFF_EFF   = 0;                          // 32*4608 = 147456 B
static constexpr int OFF_ALPHA = RING * TILE_DW * 4;         // 147456; 32 slots * 32 f32
static constexpr int OFF_MAPS  = OFF_ALPHA + 32 * 32 * 4;    // 151552; 32*32 u8
static constexpr int OFF_EV    = OFF_MAPS + 32 * 32;         // 152576; 32 i32
static constexpr int OFF_FLAGS = OFF_EV + 32 * 4;            // 152704
static constexpr int SMEM_BYTES = OFF_FLAGS + 128;           // 152832 B (<160K)

#define NINF_ (-1e4f)

__device__ __forceinline__ int bperm_i(int srclane, int v) {
  return __builtin_amdgcn_ds_bpermute(srclane << 2, v);
}
__device__ __forceinline__ float bperm_f(int srclane, float v) {
  return __int_as_float(__builtin_amdgcn_ds_bpermute(srclane << 2, __float_as_int(v)));
}
// drain LDS ops only (lgkmcnt(0)); vmcnt untouched so global prefetches stay in flight.
#define LGKM0() do { __builtin_amdgcn_s_waitcnt(0xC07F); __asm__ __volatile__("" ::: "memory"); } while (0)
#define MEMBAR() __asm__ __volatile__("" ::: "memory")

// flags layout (ints):
// [0]      = f0: wave0 published progress (steps completed)
// [1..7]   = eff flag per worker wk0..wk6 (last own tau done + 1)
// [8..14]  = bp flag per worker (next own sigma; all own < sigma are done)
// [16]     = len accumulator, [17] = last_tag

// one wave0 recurrence step: CUR = eff_t regs, NXT <- eff_{t+1} prefetch
#define W0_STEP(CUR, NXT)                                                      \
  do {                                                                         \
    if ((t & 7) == 0) {                                                        \
      LGKM0();                                                                 \
      if (tid == 0) flags[0] = t;                                              \
      const int ne0 = t + 3, ne1 = len - 6;                                    \
      const int ne = ne0 < ne1 ? ne0 : ne1;                                    \
      const int nb = t - 23;  /* alphaH ring 32, publish 8: need sigma>t-24 */ \
      for (;;) {                                                               \
        int4 fa = *(int4*)(flags_nv + 0);                                      \
        int4 fb = *(int4*)(flags_nv + 4);                                      \
        int4 fc = *(int4*)(flags_nv + 8);                                      \
        int4 fd = *(int4*)(flags_nv + 12);                                     \
        MEMBAR();                                                              \
        int em = fa.y; em = fa.z < em ? fa.z : em; em = fa.w < em ? fa.w : em; \
        em = fb.x < em ? fb.x : em; em = fb.y < em ? fb.y : em;                \
        em = fb.z < em ? fb.z : em; em = fb.w < em ? fb.w : em;                \
        int bm = fc.x; bm = fc.y < bm ? fc.y : bm; bm = fc.z < bm ? fc.z : bm; \
        bm = fc.w < bm ? fc.w : bm; bm = fd.x < bm ? fd.x : bm;                \
        bm = fd.y < bm ? fd.y : bm; bm = fd.z < bm ? fd.z : bm;                \
        if (em >= ne && bm >= nb) break;                                       \
      }                                                                        \
    }                                                                          \
    if (t + 1 < len) {                                                         \
      const float* np_ = effT + ((t + 1) & (RING - 1)) * TILE_DW + jj * CS;    \
      _Pragma("unroll")                                                        \
      for (int q = 0; q < 8; ++q) NXT[q] = *(const float4*)(np_ + 4 * q);      \
    }                                                                          \
    float qm[8];                                                               \
    _Pragma("unroll")                                                          \
    for (int q = 0; q < 8; ++q)                                                \
      qm[q] = fmaxf(fmaxf(sa[4*q+0] + CUR[q].x, sa[4*q+1] + CUR[q].y),         \
                    fmaxf(sa[4*q+2] + CUR[q].z, sa[4*q+3] + CUR[q].w));        \
    float m_ = fmaxf(fmaxf(fmaxf(qm[0], qm[1]), fmaxf(qm[2], qm[3])),          \
                     fmaxf(fmaxf(qm[4], qm[5]), fmaxf(qm[6], qm[7])));         \
    alphaH[(t & 31) * 32 + jj] = m_;                                           \
    int mi_ = __float_as_int(m_);                                              \
    _Pragma("unroll")                                                          \
    for (int i = 0; i < 32; ++i)                                               \
      sa[i] = __int_as_float(__builtin_amdgcn_readlane(mi_, i));               \
  } while (0)

extern "C" __global__ void __launch_bounds__(512, 1)
viterbi_fused(const float* __restrict__ lp, const int* __restrict__ mask,
              const int* __restrict__ startc, const int* __restrict__ endc,
              const int* __restrict__ transc, float* __restrict__ out,
              uint8_t* __restrict__ wsb)
{
  extern __shared__ char smem[];
  float*   effT   = (float*)(smem + OFF_EFF);
  float*   alphaH = (float*)(smem + OFF_ALPHA);
  uint8_t* maps   = (uint8_t*)(smem + OFF_MAPS);
  int*     Ev     = (int*)(smem + OFF_EV);
  volatile int* flags = (volatile int*)(smem + OFF_FLAGS);
  int*     flags_nv   = (int*)(smem + OFF_FLAGS);

  const int b   = blockIdx.x;
  const int tid = threadIdx.x;
  const int wid = tid >> 6;
  const int l   = tid & 63;
  const int j   = l & 31;
  const int h   = l >> 5;
  uint8_t* gback = wsb + (size_t)b * TT * 32;   // 64 KB per block in workspace

  if (tid < 24) flags_nv[tid] = 0;
  __syncthreads();
  {
    int s = 0;
#pragma unroll
    for (int k = 0; k < 4; ++k) s += mask[b * TT + k * 512 + tid];
    atomicAdd(&flags_nv[16], s);   // prefix-true mask -> sum == length
  }
  __syncthreads();
  const int len = flags_nv[16];
  const float epj = endc[j] ? 0.0f : NINF_;

  if (wid == 0) {
    // ================== recurrence wave (32-lane mirrored, alpha in SGPRs) ==
    __builtin_amdgcn_s_setprio(1);
    const int jj = j;
    float  sa[32];
    float4 eA[8], eB[8];
    {  // initial wait: all eff flags >= 4  =>  eff_0..eff_9 present
      for (;;) {
        int4 fa = *(int4*)(flags_nv + 0);
        int4 fb = *(int4*)(flags_nv + 4);
        MEMBAR();
        int em = fa.y; em = fa.z < em ? fa.z : em; em = fa.w < em ? fa.w : em;
        em = fb.x < em ? fb.x : em; em = fb.y < em ? fb.y : em;
        em = fb.z < em ? fb.z : em; em = fb.w < em ? fb.w : em;
        if (em >= 4) break;
      }
    }
    {
      const float* p0 = effT + jj * CS;
#pragma unroll
      for (int q = 0; q < 8; ++q) eA[q] = *(const float4*)(p0 + 4 * q);
      const float* p1 = effT + TILE_DW + jj * CS;
#pragma unroll
      for (int q = 0; q < 8; ++q) eB[q] = *(const float4*)(p1 + 4 * q);
    }
    {  // t = 0: alpha0 = colmax(eff0), no alpha add
      float qm[8];
#pragma unroll
      for (int q = 0; q < 8; ++q)
        qm[q] = fmaxf(fmaxf(eA[q].x, eA[q].y), fmaxf(eA[q].z, eA[q].w));
      float m = fmaxf(fmaxf(fmaxf(qm[0], qm[1]), fmaxf(qm[2], qm[3])),
                      fmaxf(fmaxf(qm[4], qm[5]), fmaxf(qm[6], qm[7])));
      alphaH[jj] = m;
      int mi = __float_as_int(m);
#pragma unroll
      for (int i = 0; i < 32; ++i)
        sa[i] = __int_as_float(__builtin_amdgcn_readlane(mi, i));
    }
    int t = 1;
    while (t < len) {
      W0_STEP(eB, eA); ++t;
      if (t >= len) break;
      W0_STEP(eA, eB); ++t;
    }
    LGKM0();
    if (tid == 0) flags[0] = len;   // unblock final bp drains
    __builtin_amdgcn_s_setprio(0);
  } else {
    // ================== 7 worker waves: eff production + bp drain ==========
    const int wk = wid - 1;                    // 0..6, owns tau == wk (mod 7)
    int pwt = wk + 2;                          // partner draining our slot's
    const int pw = pwt >= 7 ? pwt - 7 : pwt;   //   previous occupant (tau-32)
    float tp[16];
#pragma unroll
    for (int k = 0; k < 16; ++k) tp[k] = transc[(16 * h + k) * 32 + j] ? 0.0f : NINF_;
    const float spj = startc[j] ? 0.0f : NINF_;
    const float* gb = lp + (size_t)b * TT * 1024 + (size_t)(16 * h * 32 + j);

    auto DO_BP = [&](int sg) {
      const float* ap = alphaH + ((sg - 1) & 31) * 32 + h * 16;
      float4 a0 = *(const float4*)(ap + 0), a1 = *(const float4*)(ap + 4),
             a2 = *(const float4*)(ap + 8), a3 = *(const float4*)(ap + 12);
      const float* ep = effT + (sg & (RING - 1)) * TILE_DW + j * CS + h * 16;
      float4 e0 = *(const float4*)(ep + 0), e1 = *(const float4*)(ep + 4),
             e2 = *(const float4*)(ep + 8), e3 = *(const float4*)(ep + 12);
      float av[16] = {a0.x,a0.y,a0.z,a0.w, a1.x,a1.y,a1.z,a1.w,
                      a2.x,a2.y,a2.z,a2.w, a3.x,a3.y,a3.z,a3.w};
      float ev[16] = {e0.x,e0.y,e0.z,e0.w, e1.x,e1.y,e1.z,e1.w,
                      e2.x,e2.y,e2.z,e2.w, e3.x,e3.y,e3.z,e3.w};
      float bv = av[0] + ev[0]; int bi = 0;
#pragma unroll
      for (int k = 1; k < 16; ++k) {
        float c = av[k] + ev[k];
        if (c > bv) { bv = c; bi = k; }      // strict > keeps first max
      }
      float ob = bperm_f(l ^ 32, bv);
      int   oi = bperm_i(l ^ 32, bi);
      int bk = (ob > bv) ? (oi + 16) : bi;   // upper half wins only strictly
      if (l < 32) gback[(size_t)sg * 32 + l] = (uint8_t)bk;
    };

    float buf[3][16];   // HBM prefetch, 21-step lookahead (48 VGPR: no spill)
#pragma unroll
    for (int s = 0; s < 3; ++s) {
      const int tl = wk + 7 * s;
      if (tl < len) {
        const float* g = gb + (size_t)tl * 1024;
#pragma unroll
        for (int k = 0; k < 16; ++k) buf[s][k] = g[k * 32];
      }
    }
    int sigma = wk + 1;    // bp class (wk+1) mod 7, stride 7
    for (int base = wk; base < len; base += 21) {
#pragma unroll
      for (int s = 0; s < 3; ++s) {
        const int tau = base + 7 * s;
        if (tau < len) {
          if (tau >= RING) {
            const int needf = tau - RING;        // wave0 consumed old slot
            const int needb = tau - RING + 1;    // partner bp'd old slot
            for (;;) {
              int f0 = flags_nv[0]; int pb = flags_nv[8 + pw];
              MEMBAR();
              if (f0 >= needf && pb >= needb) break;
              // self-serve own bp while waiting (breaks any cross-wait cycle)
              if (sigma <= f0 && sigma < len) {
                DO_BP(sigma); sigma += 7;
                LGKM0();
                if (l == 0) flags[8 + wk] = sigma;
              }
            }
          }
          while (sigma <= tau - RING) {          // mandatory drain (f0>=tau-RING>=sigma)
            DO_BP(sigma); sigma += 7;
            LGKM0();
            if (l == 0) flags[8 + wk] = sigma;
          }
          // ---- form + write eff_tau ----
          float e[16];
          if (tau == 0) {
#pragma unroll
            for (int k = 0; k < 16; ++k) e[k] = buf[s][k] + spj;
          } else {
#pragma unroll
            for (int k = 0; k < 16; ++k) e[k] = buf[s][k] + tp[k];
          }
          if (tau == len - 1) {
#pragma unroll
            for (int k = 0; k < 16; ++k) e[k] += epj;
          }
          float* rp = effT + (tau & (RING - 1)) * TILE_DW + j * CS + h * 16;
          *(float4*)(rp + 0)  = make_float4(e[0],  e[1],  e[2],  e[3]);
          *(float4*)(rp + 4)  = make_float4(e[4],  e[5],  e[6],  e[7]);
          *(float4*)(rp + 8)  = make_float4(e[8],  e[9],  e[10], e[11]);
          *(float4*)(rp + 12) = make_float4(e[12], e[13], e[14], e[15]);
          LGKM0();
          if (l == 0) flags[1 + wk] = tau + 1;
          // ---- opportunistic bp drain (<=2) ----
          {
            int f0s = flags_nv[0];
            MEMBAR();
            int lim = (f0s < len - 1) ? f0s : (len - 1);
            int cnt = 0;
            while (cnt < 2 && sigma <= lim) { DO_BP(sigma); sigma += 7; ++cnt; }
            if (cnt) {
              LGKM0();
              if (l == 0) flags[8 + wk] = sigma;
            }
          }
          // ---- refill HBM prefetch slot (21 steps ahead) ----
          const int tn = tau + 21;
          if (tn < len) {
            const float* g = gb + (size_t)tn * 1024;
#pragma unroll
            for (int k = 0; k < 16; ++k) buf[s][k] = g[k * 32];
          }
        }
      }
    }
    // final drain
    while (sigma <= len - 1) {
      for (;;) { int f0 = flags_nv[0]; MEMBAR(); if (f0 >= sigma) break; }
      DO_BP(sigma); sigma += 7;
      LGKM0();
      if (l == 0) flags[8 + wk] = sigma;
    }
  }
  __syncthreads();

  // ================== epilogue ==================
  // stage back[] from workspace into LDS (effT region is dead now)
  uint8_t* lback = (uint8_t*)smem;
  {
    int4* dst = (int4*)lback;
    const int4* src = (const int4*)gback;
    for (int it = tid; it < TT * 32 / 16; it += 512) dst[it] = src[it];
  }
  // mlp + last_tag (wave0; alphaH region is not aliased by lback)
  if (wid == 0) {
    float v = alphaH[((len - 1) & 31) * 32 + j];
    int idx = j;
#pragma unroll
    for (int d = 1; d <= 16; d <<= 1) {
      float ov = bperm_f(l ^ d, v);
      int   oi = bperm_i(l ^ d, idx);
      if (ov > v || (ov == v && oi < idx)) { v = ov; idx = oi; }  // first-index argmax
    }
    if (tid == 0) { out[b] = v; flags_nv[17] = idx; }
  }
  __syncthreads();
  const int last_tag = flags_nv[17];

  // ---- Phase A: per-chunk backpointer map composition (32 chunks of 64) ----
  int M[4];
#pragma unroll
  for (int m = 0; m < 4; ++m) M[m] = j;
  for (int kk = 63; kk >= 0; --kk) {
#pragma unroll
    for (int m = 0; m < 4; ++m) {
      const int c = wid * 4 + m;
      const int t = c * 64 + kk;
      if (t >= 1 && t < len) {             // t>=len: identity (masked steps)
        int bt = lback[t * 32 + j];
        M[m] = bperm_i(M[m], bt);          // M <- back_t[M]
      }
    }
  }
#pragma unroll
  for (int m = 0; m < 4; ++m) if (l < 32) maps[(wid * 4 + m) * 32 + l] = (uint8_t)M[m];
  __syncthreads();

  // ---- Phase B: stitch chunk-boundary tags ----
  if (tid == 0) {
    int e = last_tag;
    Ev[31] = e;
    for (int c = 31; c >= 1; --c) { e = maps[c * 32 + e]; Ev[c - 1] = e; }
  }
  __syncthreads();

  // ---- Phase C: replay within chunks, emit tags ----
  int tg[4], kp[4];
#pragma unroll
  for (int m = 0; m < 4; ++m) { tg[m] = Ev[wid * 4 + m]; kp[m] = tg[m]; }
  for (int kk = 63; kk >= 0; --kk) {
#pragma unroll
    for (int m = 0; m < 4; ++m) {
      const int c = wid * 4 + m;
      const int p = c * 64 + kk;
      kp[m] = (l == kk) ? tg[m] : kp[m];   // lane kk keeps tag@p
      if (p >= 1 && p < len) {
        int bt = lback[p * 32 + j];
        tg[m] = bperm_i(tg[m], bt);        // tag@(p-1) = back_p[tag@p]
      }
    }
  }
#pragma unroll
  for (int m = 0; m < 4; ++m) {
    const int c = wid * 4 + m;
    const int pos = c * 64 + l;
    out[64 + b * TT + pos] = (pos < len) ? (float)kp[m] : -1.0f;
  }
}

extern "C" void kernel_launch(void* const* d_in, const int* in_sizes, int n_in,
                              void* d_out, int out_size, void* d_ws, size_t ws_size,
                              hipStream_t stream) {
  const float* lp     = (const float*)d_in[0];
  const int*   mask   = (const int*)d_in[1];
  const int*   startc = (const int*)d_in[2];
  const int*   endc   = (const int*)d_in[3];
  const int*   transc = (const int*)d_in[4];
  float* out = (float*)d_out;
  (void)ws_size; (void)n_in; (void)in_sizes; (void)out_size;
  hipFuncSetAttribute((const void*)viterbi_fused,
                      hipFuncAttributeMaxDynamicSharedMemorySize, SMEM_BYTES);
  viterbi_fused<<<dim3(64), dim3(512), SMEM_BYTES, stream>>>(
      lp, mask, startc, endc, transc, out, (uint8_t*)d_ws);
}

// Round 2
// 1093.665 us; speedup vs baseline: 1.3244x; 1.0102x over previous
//
#include <hip/hip_runtime.h>
#include <stdint.h>

// Constrained Viterbi decode, B=64, T=2048, N=32. 64 blocks x 512 threads.
//
// v3: wave0 (serial recurrence) rewritten to use all 64 lanes productively.
// Previously both 32-lane halves mirrored the same 63-VALU-op column reduction
// + 32 v_readlane broadcast (~260cy issue) yet measured 687 cy/step.
// Now: lane (j,h) reduces i in [16h,16h+16): 16 adds + 8 v_max3, cross-half
// combine via 1 ds_bpermute(l^32) + max, alpha broadcast via 16 ds_bpermute
// pulls (precomputed lane addrs) instead of 32 readlanes. LDS read volume
// halves (4 KB/step). Eff-prefetch gate widened t+3 -> t+9 (fixes a latent
// staleness race: reads for eff_{t+1..t+8} are issued between polls).
// Workers (7 producers + bp drain) and epilogue unchanged from v2 (proven).
// Max is associative in fp32 and add pairings are unchanged -> bit-exact.

static constexpr int TT = 2048;
static constexpr int RING = 32;            // eff ring slots (power of 2)
static constexpr int CS = 36;              // col stride (dwords): 144B, 16B-aligned
static constexpr int TILE_DW = 32 * CS;    // 1152 dwords / tile
static constexpr int OFF_EFF   = 0;                          // 32*4608 = 147456 B
static constexpr int OFF_ALPHA = RING * TILE_DW * 4;         // 147456; 32 slots * 32 f32
static constexpr int OFF_MAPS  = OFF_ALPHA + 32 * 32 * 4;    // 151552; 32*32 u8
static constexpr int OFF_EV    = OFF_MAPS + 32 * 32;         // 152576; 32 i32
static constexpr int OFF_FLAGS = OFF_EV + 32 * 4;            // 152704
static constexpr int SMEM_BYTES = OFF_FLAGS + 128;           // 152832 B (<160K)

#define NINF_ (-1e4f)

__device__ __forceinline__ int bperm_i(int srclane, int v) {
  return __builtin_amdgcn_ds_bpermute(srclane << 2, v);
}
__device__ __forceinline__ float bperm_f(int srclane, float v) {
  return __int_as_float(__builtin_amdgcn_ds_bpermute(srclane << 2, __float_as_int(v)));
}
__device__ __forceinline__ float bperm_fb(int byteaddr, float v) {
  return __int_as_float(__builtin_amdgcn_ds_bpermute(byteaddr, __float_as_int(v)));
}
__device__ __forceinline__ float m3(float a, float b, float c) {
  return fmaxf(fmaxf(a, b), c);   // clang fuses to v_max3_f32
}
// drain LDS ops only (lgkmcnt(0)); vmcnt untouched so global prefetches stay in flight.
#define LGKM0() do { __builtin_amdgcn_s_waitcnt(0xC07F); __asm__ __volatile__("" ::: "memory"); } while (0)
#define MEMBAR() __asm__ __volatile__("" ::: "memory")

// flags layout (ints):
// [0]      = f0: wave0 published progress (steps completed)
// [1..7]   = eff flag per worker wk0..wk6 (last own tau done + 1)
// [8..14]  = bp flag per worker (next own sigma; all own < sigma are done)
// [16]     = len accumulator, [17] = last_tag

// one wave0 recurrence step: CUR = eff_t regs (this lane's 16 i-values for
// col j, half h), NXT <- eff_{t+1} prefetch. ab[k] = alpha_{t-1}[16h+k].
#define W0_STEP(CUR, NXT)                                                      \
  do {                                                                         \
    if ((t & 7) == 0) {                                                        \
      LGKM0();                                                                 \
      if (tid == 0) flags[0] = t;                                              \
      const int ne0 = t + 9, ne1 = len - 6;                                    \
      const int ne = ne0 < ne1 ? ne0 : ne1;                                    \
      const int nb = t - 23;  /* alphaH ring 32, publish 8: need sigma>t-24 */ \
      for (;;) {                                                               \
        int4 fa = *(int4*)(flags_nv + 0);                                      \
        int4 fb = *(int4*)(flags_nv + 4);                                      \
        int4 fc = *(int4*)(flags_nv + 8);                                      \
        int4 fd = *(int4*)(flags_nv + 12);                                     \
        MEMBAR();                                                              \
        int em = fa.y; em = fa.z < em ? fa.z : em; em = fa.w < em ? fa.w : em; \
        em = fb.x < em ? fb.x : em; em = fb.y < em ? fb.y : em;                \
        em = fb.z < em ? fb.z : em; em = fb.w < em ? fb.w : em;                \
        int bm = fc.x; bm = fc.y < bm ? fc.y : bm; bm = fc.z < bm ? fc.z : bm; \
        bm = fc.w < bm ? fc.w : bm; bm = fd.x < bm ? fd.x : bm;                \
        bm = fd.y < bm ? fd.y : bm; bm = fd.z < bm ? fd.z : bm;                \
        if (em >= ne && bm >= nb) break;                                       \
      }                                                                        \
    }                                                                          \
    if (t + 1 < len) {                                                         \
      const float* np_ = effT + ((t + 1) & (RING - 1)) * TILE_DW + ebase;      \
      _Pragma("unroll")                                                        \
      for (int g = 0; g < 4; ++g) NXT[g] = *(const float4*)(np_ + 4 * g);      \
    }                                                                          \
    float c_[16];                                                              \
    _Pragma("unroll")                                                          \
    for (int g = 0; g < 4; ++g) {                                              \
      c_[4*g+0] = ab[4*g+0] + CUR[g].x;                                        \
      c_[4*g+1] = ab[4*g+1] + CUR[g].y;                                        \
      c_[4*g+2] = ab[4*g+2] + CUR[g].z;                                        \
      c_[4*g+3] = ab[4*g+3] + CUR[g].w;                                        \
    }                                                                          \
    float t0_ = m3(c_[0], c_[1], c_[2]),  t1_ = m3(c_[3], c_[4], c_[5]);       \
    float t2_ = m3(c_[6], c_[7], c_[8]),  t3_ = m3(c_[9], c_[10], c_[11]);     \
    float t4_ = m3(c_[12], c_[13], c_[14]);                                    \
    float pm_ = fmaxf(m3(t0_, t1_, c_[15]), m3(t2_, t3_, t4_));                \
    float m_ = fmaxf(pm_, bperm_f(l ^ 32, pm_));                               \
    alphaH[(t & 31) * 32 + j] = m_;   /* h=0/1 write same addr+value: ok */    \
    _Pragma("unroll")                                                          \
    for (int k = 0; k < 16; ++k) ab[k] = bperm_fb(aba[k], m_);                 \
  } while (0)

extern "C" __global__ void __launch_bounds__(512, 1)
viterbi_fused(const float* __restrict__ lp, const int* __restrict__ mask,
              const int* __restrict__ startc, const int* __restrict__ endc,
              const int* __restrict__ transc, float* __restrict__ out,
              uint8_t* __restrict__ wsb)
{
  extern __shared__ char smem[];
  float*   effT   = (float*)(smem + OFF_EFF);
  float*   alphaH = (float*)(smem + OFF_ALPHA);
  uint8_t* maps   = (uint8_t*)(smem + OFF_MAPS);
  int*     Ev     = (int*)(smem + OFF_EV);
  volatile int* flags = (volatile int*)(smem + OFF_FLAGS);
  int*     flags_nv   = (int*)(smem + OFF_FLAGS);

  const int b   = blockIdx.x;
  const int tid = threadIdx.x;
  const int wid = tid >> 6;
  const int l   = tid & 63;
  const int j   = l & 31;
  const int h   = l >> 5;
  uint8_t* gback = wsb + (size_t)b * TT * 32;   // 64 KB per block in workspace

  if (tid < 24) flags_nv[tid] = 0;
  __syncthreads();
  {
    int s = 0;
#pragma unroll
    for (int k = 0; k < 4; ++k) s += mask[b * TT + k * 512 + tid];
    atomicAdd(&flags_nv[16], s);   // prefix-true mask -> sum == length
  }
  __syncthreads();
  const int len = flags_nv[16];
  const float epj = endc[j] ? 0.0f : NINF_;

  if (wid == 0) {
    // ========== recurrence wave: 64 lanes, half-split i-reduction ==========
    __builtin_amdgcn_s_setprio(1);
    const int ebase = j * CS + h * 16;   // this lane's 16 i-slots of col j
    const int habase = h << 6;           // bpermute byte base: lane 16h
    int aba[16];
#pragma unroll
    for (int k = 0; k < 16; ++k) aba[k] = habase + (k << 2);
    float4 eA[4], eB[4];
    float  ab[16];
    {  // initial wait: all eff flags >= 9  =>  eff_0..eff_8 present
       // (covers prefetches issued at steps 0..7 before the first poll at t=8)
      for (;;) {
        int4 fa = *(int4*)(flags_nv + 0);
        int4 fb = *(int4*)(flags_nv + 4);
        MEMBAR();
        int em = fa.y; em = fa.z < em ? fa.z : em; em = fa.w < em ? fa.w : em;
        em = fb.x < em ? fb.x : em; em = fb.y < em ? fb.y : em;
        em = fb.z < em ? fb.z : em; em = fb.w < em ? fb.w : em;
        if (em >= 9) break;
      }
    }
    {
      const float* p0 = effT + ebase;
#pragma unroll
      for (int g = 0; g < 4; ++g) eA[g] = *(const float4*)(p0 + 4 * g);
      const float* p1 = effT + TILE_DW + ebase;
#pragma unroll
      for (int g = 0; g < 4; ++g) eB[g] = *(const float4*)(p1 + 4 * g);
    }
    {  // t = 0: alpha0 = colmax(eff0), no alpha add
      float t0_ = m3(eA[0].x, eA[0].y, eA[0].z);
      float t1_ = m3(eA[0].w, eA[1].x, eA[1].y);
      float t2_ = m3(eA[1].z, eA[1].w, eA[2].x);
      float t3_ = m3(eA[2].y, eA[2].z, eA[2].w);
      float t4_ = m3(eA[3].x, eA[3].y, eA[3].z);
      float pm_ = fmaxf(m3(t0_, t1_, eA[3].w), m3(t2_, t3_, t4_));
      float m_ = fmaxf(pm_, bperm_f(l ^ 32, pm_));
      alphaH[j] = m_;
#pragma unroll
      for (int k = 0; k < 16; ++k) ab[k] = bperm_fb(aba[k], m_);
    }
    int t = 1;
    while (t < len) {
      W0_STEP(eB, eA); ++t;
      if (t >= len) break;
      W0_STEP(eA, eB); ++t;
    }
    LGKM0();
    if (tid == 0) flags[0] = len;   // unblock final bp drains
    __builtin_amdgcn_s_setprio(0);
  } else {
    // ================== 7 worker waves: eff production + bp drain ==========
    const int wk = wid - 1;                    // 0..6, owns tau == wk (mod 7)
    int pwt = wk + 2;                          // partner draining our slot's
    const int pw = pwt >= 7 ? pwt - 7 : pwt;   //   previous occupant (tau-32)
    float tp[16];
#pragma unroll
    for (int k = 0; k < 16; ++k) tp[k] = transc[(16 * h + k) * 32 + j] ? 0.0f : NINF_;
    const float spj = startc[j] ? 0.0f : NINF_;
    const float* gb = lp + (size_t)b * TT * 1024 + (size_t)(16 * h * 32 + j);

    auto DO_BP = [&](int sg) {
      const float* ap = alphaH + ((sg - 1) & 31) * 32 + h * 16;
      float4 a0 = *(const float4*)(ap + 0), a1 = *(const float4*)(ap + 4),
             a2 = *(const float4*)(ap + 8), a3 = *(const float4*)(ap + 12);
      const float* ep = effT + (sg & (RING - 1)) * TILE_DW + j * CS + h * 16;
      float4 e0 = *(const float4*)(ep + 0), e1 = *(const float4*)(ep + 4),
             e2 = *(const float4*)(ep + 8), e3 = *(const float4*)(ep + 12);
      float av[16] = {a0.x,a0.y,a0.z,a0.w, a1.x,a1.y,a1.z,a1.w,
                      a2.x,a2.y,a2.z,a2.w, a3.x,a3.y,a3.z,a3.w};
      float ev[16] = {e0.x,e0.y,e0.z,e0.w, e1.x,e1.y,e1.z,e1.w,
                      e2.x,e2.y,e2.z,e2.w, e3.x,e3.y,e3.z,e3.w};
      float bv = av[0] + ev[0]; int bi = 0;
#pragma unroll
      for (int k = 1; k < 16; ++k) {
        float c = av[k] + ev[k];
        if (c > bv) { bv = c; bi = k; }      // strict > keeps first max
      }
      float ob = bperm_f(l ^ 32, bv);
      int   oi = bperm_i(l ^ 32, bi);
      int bk = (ob > bv) ? (oi + 16) : bi;   // upper half wins only strictly
      if (l < 32) gback[(size_t)sg * 32 + l] = (uint8_t)bk;
    };

    float buf[3][16];   // HBM prefetch, 21-step lookahead (48 VGPR: no spill)
#pragma unroll
    for (int s = 0; s < 3; ++s) {
      const int tl = wk + 7 * s;
      if (tl < len) {
        const float* g = gb + (size_t)tl * 1024;
#pragma unroll
        for (int k = 0; k < 16; ++k) buf[s][k] = g[k * 32];
      }
    }
    int sigma = wk + 1;    // bp class (wk+1) mod 7, stride 7
    for (int base = wk; base < len; base += 21) {
#pragma unroll
      for (int s = 0; s < 3; ++s) {
        const int tau = base + 7 * s;
        if (tau < len) {
          if (tau >= RING) {
            const int needf = tau - RING;        // wave0 consumed old slot
            const int needb = tau - RING + 1;    // partner bp'd old slot
            for (;;) {
              int f0 = flags_nv[0]; int pb = flags_nv[8 + pw];
              MEMBAR();
              if (f0 >= needf && pb >= needb) break;
              // self-serve own bp while waiting (breaks any cross-wait cycle)
              if (sigma <= f0 && sigma < len) {
                DO_BP(sigma); sigma += 7;
                LGKM0();
                if (l == 0) flags[8 + wk] = sigma;
              }
            }
          }
          while (sigma <= tau - RING) {          // mandatory drain (f0>=tau-RING>=sigma)
            DO_BP(sigma); sigma += 7;
            LGKM0();
            if (l == 0) flags[8 + wk] = sigma;
          }
          // ---- form + write eff_tau ----
          float e[16];
          if (tau == 0) {
#pragma unroll
            for (int k = 0; k < 16; ++k) e[k] = buf[s][k] + spj;
          } else {
#pragma unroll
            for (int k = 0; k < 16; ++k) e[k] = buf[s][k] + tp[k];
          }
          if (tau == len - 1) {
#pragma unroll
            for (int k = 0; k < 16; ++k) e[k] += epj;
          }
          float* rp = effT + (tau & (RING - 1)) * TILE_DW + j * CS + h * 16;
          *(float4*)(rp + 0)  = make_float4(e[0],  e[1],  e[2],  e[3]);
          *(float4*)(rp + 4)  = make_float4(e[4],  e[5],  e[6],  e[7]);
          *(float4*)(rp + 8)  = make_float4(e[8],  e[9],  e[10], e[11]);
          *(float4*)(rp + 12) = make_float4(e[12], e[13], e[14], e[15]);
          LGKM0();
          if (l == 0) flags[1 + wk] = tau + 1;
          // ---- opportunistic bp drain (<=2) ----
          {
            int f0s = flags_nv[0];
            MEMBAR();
            int lim = (f0s < len - 1) ? f0s : (len - 1);
            int cnt = 0;
            while (cnt < 2 && sigma <= lim) { DO_BP(sigma); sigma += 7; ++cnt; }
            if (cnt) {
              LGKM0();
              if (l == 0) flags[8 + wk] = sigma;
            }
          }
          // ---- refill HBM prefetch slot (21 steps ahead) ----
          const int tn = tau + 21;
          if (tn < len) {
            const float* g = gb + (size_t)tn * 1024;
#pragma unroll
            for (int k = 0; k < 16; ++k) buf[s][k] = g[k * 32];
          }
        }
      }
    }
    // final drain
    while (sigma <= len - 1) {
      for (;;) { int f0 = flags_nv[0]; MEMBAR(); if (f0 >= sigma) break; }
      DO_BP(sigma); sigma += 7;
      LGKM0();
      if (l == 0) flags[8 + wk] = sigma;
    }
  }
  __syncthreads();

  // ================== epilogue ==================
  // stage back[] from workspace into LDS (effT region is dead now)
  uint8_t* lback = (uint8_t*)smem;
  {
    int4* dst = (int4*)lback;
    const int4* src = (const int4*)gback;
    for (int it = tid; it < TT * 32 / 16; it += 512) dst[it] = src[it];
  }
  // mlp + last_tag (wave0; alphaH region is not aliased by lback)
  if (wid == 0) {
    float v = alphaH[((len - 1) & 31) * 32 + j];
    int idx = j;
#pragma unroll
    for (int d = 1; d <= 16; d <<= 1) {
      float ov = bperm_f(l ^ d, v);
      int   oi = bperm_i(l ^ d, idx);
      if (ov > v || (ov == v && oi < idx)) { v = ov; idx = oi; }  // first-index argmax
    }
    if (tid == 0) { out[b] = v; flags_nv[17] = idx; }
  }
  __syncthreads();
  const int last_tag = flags_nv[17];

  // ---- Phase A: per-chunk backpointer map composition (32 chunks of 64) ----
  int M[4];
#pragma unroll
  for (int m = 0; m < 4; ++m) M[m] = j;
  for (int kk = 63; kk >= 0; --kk) {
#pragma unroll
    for (int m = 0; m < 4; ++m) {
      const int c = wid * 4 + m;
      const int t = c * 64 + kk;
      if (t >= 1 && t < len) {             // t>=len: identity (masked steps)
        int bt = lback[t * 32 + j];
        M[m] = bperm_i(M[m], bt);          // M <- back_t[M]
      }
    }
  }
#pragma unroll
  for (int m = 0; m < 4; ++m) if (l < 32) maps[(wid * 4 + m) * 32 + l] = (uint8_t)M[m];
  __syncthreads();

  // ---- Phase B: stitch chunk-boundary tags ----
  if (tid == 0) {
    int e = last_tag;
    Ev[31] = e;
    for (int c = 31; c >= 1; --c) { e = maps[c * 32 + e]; Ev[c - 1] = e; }
  }
  __syncthreads();

  // ---- Phase C: replay within chunks, emit tags ----
  int tg[4], kp[4];
#pragma unroll
  for (int m = 0; m < 4; ++m) { tg[m] = Ev[wid * 4 + m]; kp[m] = tg[m]; }
  for (int kk = 63; kk >= 0; --kk) {
#pragma unroll
    for (int m = 0; m < 4; ++m) {
      const int c = wid * 4 + m;
      const int p = c * 64 + kk;
      kp[m] = (l == kk) ? tg[m] : kp[m];   // lane kk keeps tag@p
      if (p >= 1 && p < len) {
        int bt = lback[p * 32 + j];
        tg[m] = bperm_i(tg[m], bt);        // tag@(p-1) = back_p[tag@p]
      }
    }
  }
#pragma unroll
  for (int m = 0; m < 4; ++m) {
    const int c = wid * 4 + m;
    const int pos = c * 64 + l;
    out[64 + b * TT + pos] = (pos < len) ? (float)kp[m] : -1.0f;
  }
}

extern "C" void kernel_launch(void* const* d_in, const int* in_sizes, int n_in,
                              void* d_out, int out_size, void* d_ws, size_t ws_size,
                              hipStream_t stream) {
  const float* lp     = (const float*)d_in[0];
  const int*   mask   = (const int*)d_in[1];
  const int*   startc = (const int*)d_in[2];
  const int*   endc   = (const int*)d_in[3];
  const int*   transc = (const int*)d_in[4];
  float* out = (float*)d_out;
  (void)ws_size; (void)n_in; (void)in_sizes; (void)out_size;
  hipFuncSetAttribute((const void*)viterbi_fused,
                      hipFuncAttributeMaxDynamicSharedMemorySize, SMEM_BYTES);
  viterbi_fused<<<dim3(64), dim3(512), SMEM_BYTES, stream>>>(
      lp, mask, startc, endc, transc, out, (uint8_t*)d_ws);
}